// Round 15
// baseline (118.036 us; speedup 1.0000x reference)
//
#include <hip/hip_runtime.h>
#include <math.h>

// B=2, T=2048, D=768, H=12, HD=64
typedef __attribute__((ext_vector_type(8))) __bf16 bf16x8;
typedef __attribute__((ext_vector_type(4))) __bf16 bf16x4;
typedef __attribute__((ext_vector_type(4))) float f32x4;

#define GLOAD_LDS16(gsrc, ldst) \
  __builtin_amdgcn_global_load_lds((__attribute__((address_space(1))) const void*)(gsrc), \
                                   (__attribute__((address_space(3))) void*)(ldst), 16, 0, 0)

__device__ __forceinline__ float fexp2(float x) {
#if __has_builtin(__builtin_amdgcn_exp2f)
  return __builtin_amdgcn_exp2f(x);
#else
  return exp2f(x);
#endif
}

__global__ void cvt_bf16_kernel(const float* __restrict__ in, __bf16* __restrict__ out, int n4) {
  int i = blockIdx.x * 256 + threadIdx.x;
  if (i < n4) {
    float4 f = ((const float4*)in)[i];
    bf16x4 o;
    o[0] = (__bf16)f.x; o[1] = (__bf16)f.y; o[2] = (__bf16)f.z; o[3] = (__bf16)f.w;
    ((bf16x4*)out)[i] = o;
  }
}

// Tiled transpose-convert: out[C][R] = (bf16) in[R][C]. 32x32 tiles via LDS.
__global__ __launch_bounds__(256)
void cvtT_bf16_kernel(const float* __restrict__ in, __bf16* __restrict__ out, int R, int C) {
  __shared__ float t[32][33];
  int c0 = blockIdx.x * 32, r0 = blockIdx.y * 32;
  int tc = threadIdx.x & 31, tr = threadIdx.x >> 5;
#pragma unroll
  for (int i = 0; i < 4; ++i)
    t[tr + 8 * i][tc] = in[(size_t)(r0 + tr + 8 * i) * C + c0 + tc];
  __syncthreads();
#pragma unroll
  for (int i = 0; i < 4; ++i)
    out[(size_t)(c0 + tr + 8 * i) * R + r0 + tc] = (__bf16)t[tc][tr + 8 * i];
}

// TN GEMM: C[M][N] = A[M][K] * B[N][K]^T (+bias). BMxBN tile, BK=64, WAVES waves.
// BUFS=2: simple-sync double buffer {barrier; stage(t+1,nxt); compute(cur)} —
//   stage latency hides under compute + the CO-RESIDENT block (needs >=2 blocks/CU;
//   R14 post-mortem: 1 block/CU leaves the CU empty at every barrier, 3x pipe-sum).
// BUFS=3: counted-vmcnt distance-2 pipeline (for kernels at 1-2 blocks/CU).
// XCD mapping: rect (mg,ng); NNX n-slices per XCD -> B slice L2-resident.
template<int EPI, int BM, int BN, int WAVES, int WGM, int WGN, int BUFS>
__global__ __launch_bounds__(WAVES * 64, 3)
void gemm_tn_kernel(const __bf16* __restrict__ A, const __bf16* __restrict__ Bm,
                    const float* __restrict__ bias, float* __restrict__ outF,
                    __bf16* __restrict__ qo, __bf16* __restrict__ ko, __bf16* __restrict__ vo,
                    int M, int N, int K, int NBX, int NNX, int PPX) {
  constexpr int NTA = BM / 16, NTB = BN / 16;
  constexpr int NA = 2 * NTA;               // A segments (2 k-halves)
  constexpr int NSEG = 2 * NTA + 2 * NTB;   // 1KB segments per K-step
  constexpr int LPTH = (NSEG + WAVES - 1) / WAVES;
  constexpr int LPTR = NSEG % WAVES;        // waves < LPTR stage LPTH, rest LPTH-1
  constexpr int LLO = (LPTR == 0) ? LPTH : LPTH - 1;
  constexpr int AM = NTA / WGM;
  constexpr int BNF = NTB / WGN;
  const int lane = threadIdx.x & 63;
  const int wave = threadIdx.x >> 6;
  const int r16 = lane & 15, g = lane >> 4;
  const int id = blockIdx.x;
  const int xcd = id & 7, slot = id >> 3;
  const int nxn = NBX / NNX;
  const int mg = xcd / nxn, ng = xcd % nxn;
  const int lp = slot / NNX, ln = slot - (slot / NNX) * NNX;
  const int mBase = (mg * PPX + lp) * BM, nBase = (ng * NNX + ln) * BN;
  __shared__ __align__(16) __bf16 lds[BUFS][NSEG * 512];

  f32x4 acc[AM][BNF];
#pragma unroll
  for (int i = 0; i < AM; ++i)
#pragma unroll
    for (int j = 0; j < BNF; ++j) acc[i][j] = (f32x4){0.f, 0.f, 0.f, 0.f};

  const int mw = (wave / WGN) * AM;
  const int nw = (wave % WGN) * BNF;

  auto stage = [&](int ke, int b) {
#pragma unroll
    for (int i = 0; i < LPTH; ++i) {
      int s = wave + i * WAVES;             // interleaved; guard is wave-uniform
      if (LPTR == 0 || s < NSEG) {
        int isB = (s >= NA);
        int sb = isB ? s - NA : s;
        int nt = isB ? NTB : NTA;
        int ks = sb / nt, t8 = sb - ks * nt;
        int row = (isB ? nBase : mBase) + t8 * 16 + r16;
        const __bf16* src = (isB ? Bm : A) + (size_t)row * K + ke + ks * 32 + g * 8;
        GLOAD_LDS16(src, &lds[b][s * 512]);
      }
    }
  };

  auto mfma_step = [&](const __bf16* L) {
#pragma unroll
    for (int ks = 0; ks < 2; ++ks) {
      bf16x8 af[AM], bfr[BNF];
#pragma unroll
      for (int i = 0; i < AM; ++i)
        af[i] = *(const bf16x8*)&L[((ks * NTA + mw + i) * 64 + lane) * 8];
#pragma unroll
      for (int j = 0; j < BNF; ++j)
        bfr[j] = *(const bf16x8*)&L[((NA + ks * NTB + nw + j) * 64 + lane) * 8];
      __builtin_amdgcn_s_setprio(1);
#pragma unroll
      for (int i = 0; i < AM; ++i)
#pragma unroll
        for (int j = 0; j < BNF; ++j)
          acc[i][j] = __builtin_amdgcn_mfma_f32_16x16x32_bf16(af[i], bfr[j], acc[i][j], 0, 0, 0);
      __builtin_amdgcn_s_setprio(0);
    }
  };

  const int nt = K >> 6;
  if constexpr (BUFS == 2) {
    stage(0, 0);
    int cur = 0;
    for (int t = 0; t < nt; ++t) {
      __syncthreads();                     // drains stage(cur); guards buffer reuse
      if (t + 1 < nt) stage((t + 1) << 6, cur ^ 1);
      mfma_step(lds[cur]);
      cur ^= 1;
    }
  } else {
    stage(0, 0);
    stage(64, 1);
    int cur = 0;
    for (int t = 0; t < nt; ++t) {
      if (t + 1 < nt) {
        if (LPTR != 0 && wave < LPTR) asm volatile("s_waitcnt vmcnt(%0)" :: "i"(LPTH) : "memory");
        else                          asm volatile("s_waitcnt vmcnt(%0)" :: "i"(LLO) : "memory");
      } else {
        asm volatile("s_waitcnt vmcnt(0)" ::: "memory");
      }
      __builtin_amdgcn_sched_barrier(0);
      __builtin_amdgcn_s_barrier();
      __builtin_amdgcn_sched_barrier(0);
      int nxt = cur + 2; if (nxt >= 3) nxt -= 3;
      if (t + 2 < nt) stage((t + 2) << 6, nxt);
      mfma_step(lds[cur]);
      if (++cur == 3) cur = 0;
    }
  }

#pragma unroll
  for (int i = 0; i < AM; ++i) {
#pragma unroll
    for (int j = 0; j < BNF; ++j) {
      int c = nBase + (nw + j) * 16 + r16;
      float bb = bias[c];
#pragma unroll
      for (int e = 0; e < 4; ++e) {
        int r = mBase + (mw + i) * 16 + g * 4 + e;
        float val = acc[i][j][e] + bb;
        if (EPI == 0) {
          int which = c / 768;             // 0:q 1:k 2:v (per element; tiles may straddle)
          int cc = c - which * 768;
          int hh = cc >> 6, dd = cc & 63;
          int bI = r >> 11, tt = r & 2047;
          if (which == 0) {
            // fold 1/sqrt(64) * log2(e) into q (softmax runs in exp2 space)
            qo[(((size_t)(bI * 12 + hh)) * 2048 + tt) * 64 + dd] = (__bf16)(val * 0.180336880f);
          } else if (which == 1) {
            ko[(((size_t)(bI * 12 + hh)) * 2048 + tt) * 64 + dd] = (__bf16)val;
          } else {
            vo[(((size_t)(bI * 12 + hh)) * 64 + dd) * 2048 + tt] = (__bf16)val;  // V^T [B,H,64,T]
          }
        } else {
          outF[(size_t)r * N + c] = val;
        }
      }
    }
  }
}

// Flash attention, causal, swapped-QK^T, O^T accumulation, causal-paired tiles,
// strip-split 4-wave blocks. (unchanged from R12 — isolated)
__global__ __launch_bounds__(256, 2)
void attn_kernel(const __bf16* __restrict__ qg, const __bf16* __restrict__ kg,
                 const __bf16* __restrict__ vtg, __bf16* __restrict__ yatt) {
  const int id = blockIdx.x;
  const int chunk = id & 7, within = id >> 3;   // XCD chunk = 3 heads (L2-resident K/V)
  const int bh = chunk * 3 + (within >> 5);
  const int a = within & 31, p = 63 - a;        // paired 32-row q-tiles
  const int Ka = (a >> 1) + 1, Kp = (p >> 1) + 1;   // Kp > Ka always
  const int lane = threadIdx.x & 63, wave = threadIdx.x >> 6;  // wave 0..3
  const int r16 = lane & 15, g = lane >> 4;
  const int bI = bh / 12, h = bh - bI * 12;
  const size_t headoff = (size_t)bh * 2048 * 64;
  const __bf16* Q = qg + headoff;
  const __bf16* Kh = kg + headoff;
  const __bf16* VT = vtg + headoff;             // [64][2048]

  __shared__ __align__(16) __bf16 Kbuf[2][4096];   // [64 k-rows][8 chunks] swizzled
  __shared__ __align__(16) __bf16 Vbuf[2][4096];   // [64 d-rows][8 chunks] swizzled
  __shared__ __align__(16) __bf16 Plds[4][16][72]; // per-wave strip

  const int myTile = (wave < 2) ? p : a;
  const int myKt   = (wave < 2) ? Kp : Ka;
  const int rowQ   = myTile * 32 + (wave & 1) * 16 + r16;

  bf16x8 qf[2];
#pragma unroll
  for (int ks = 0; ks < 2; ++ks)
    qf[ks] = *(const bf16x8*)&Q[(size_t)rowQ * 64 + ks * 32 + g * 8];

  int srow[2], scl[2];
#pragma unroll
  for (int i = 0; i < 2; ++i) {
    int c = (i * 4 + wave) * 64 + lane;
    srow[i] = c >> 3;
    scl[i] = (c & 7) ^ (srow[i] & 7);
  }
  auto stage = [&](int kt, int b) {
#pragma unroll
    for (int i = 0; i < 2; ++i) {
      GLOAD_LDS16(&Kh[(size_t)(kt * 64 + srow[i]) * 64 + scl[i] * 8], &Kbuf[b][(i * 4 + wave) * 512]);
      GLOAD_LDS16(&VT[(size_t)srow[i] * 2048 + kt * 64 + scl[i] * 8], &Vbuf[b][(i * 4 + wave) * 512]);
    }
  };

  f32x4 o[4];
#pragma unroll
  for (int j = 0; j < 4; ++j) o[j] = (f32x4){0.f, 0.f, 0.f, 0.f};
  float l = 0.f;

  stage(0, 0);
  for (int kt = 0; kt < Kp; ++kt) {
    const int cur = kt & 1;
    __syncthreads();
    if (kt + 1 < Kp) stage(kt + 1, cur ^ 1);
    if (kt < myKt) {
      f32x4 st[4];
#pragma unroll
      for (int j = 0; j < 4; ++j) st[j] = (f32x4){0.f, 0.f, 0.f, 0.f};
      __builtin_amdgcn_s_setprio(1);
#pragma unroll
      for (int ks = 0; ks < 2; ++ks)
#pragma unroll
        for (int j = 0; j < 4; ++j) {
          int row = j * 16 + r16;
          int cp = (ks * 4 + g) ^ (row & 7);
          bf16x8 kf = *(const bf16x8*)&Kbuf[cur][(row * 8 + cp) * 8];
          st[j] = __builtin_amdgcn_mfma_f32_16x16x32_bf16(kf, qf[ks], st[j], 0, 0, 0);
        }
      __builtin_amdgcn_s_setprio(0);
      bf16x8 vf[2][4];
#pragma unroll
      for (int ks = 0; ks < 2; ++ks)
#pragma unroll
        for (int dj = 0; dj < 4; ++dj) {
          int row = dj * 16 + r16;
          int cp = (ks * 4 + g) ^ (row & 7);
          vf[ks][dj] = *(const bf16x8*)&Vbuf[cur][(row * 8 + cp) * 8];
        }
      if (kt == myKt - 1) {
#pragma unroll
        for (int j = 0; j < 4; ++j)
#pragma unroll
          for (int e = 0; e < 4; ++e)
            if (kt * 64 + j * 16 + 4 * g + e > rowQ) st[j][e] = -INFINITY;
      }
      float ls = 0.f;
#pragma unroll
      for (int j = 0; j < 4; ++j)
#pragma unroll
        for (int e = 0; e < 4; ++e) {
          float pv = fexp2(st[j][e]);
          st[j][e] = pv;
          ls += pv;
        }
      ls += __shfl_xor(ls, 16, 64);
      ls += __shfl_xor(ls, 32, 64);
      l += ls;
#pragma unroll
      for (int j = 0; j < 4; ++j) {
        bf16x4 pk;
#pragma unroll
        for (int e = 0; e < 4; ++e) pk[e] = (__bf16)st[j][e];
        *(bf16x4*)&Plds[wave][r16][j * 16 + 4 * g] = pk;
      }
      __builtin_amdgcn_s_setprio(1);
#pragma unroll
      for (int ks = 0; ks < 2; ++ks) {
        bf16x8 pf = *(const bf16x8*)&Plds[wave][r16][ks * 32 + g * 8];
#pragma unroll
        for (int dj = 0; dj < 4; ++dj)
          o[dj] = __builtin_amdgcn_mfma_f32_16x16x32_bf16(vf[ks][dj], pf, o[dj], 0, 0, 0);
      }
      __builtin_amdgcn_s_setprio(0);
    }
  }

  float inv = 1.0f / l;
#pragma unroll
  for (int dj = 0; dj < 4; ++dj) {
    bf16x4 ov;
#pragma unroll
    for (int e = 0; e < 4; ++e) ov[e] = (__bf16)(o[dj][e] * inv);
    *(bf16x4*)&yatt[((size_t)(bI * 2048 + rowQ)) * 768 + h * 64 + dj * 16 + 4 * g] = ov;
  }
}

extern "C" void kernel_launch(void* const* d_in, const int* in_sizes, int n_in,
                              void* d_out, int out_size, void* d_ws, size_t ws_size,
                              hipStream_t stream) {
  (void)in_sizes; (void)n_in; (void)out_size; (void)ws_size;
  const float* x     = (const float*)d_in[0];
  const float* w_qkv = (const float*)d_in[1];
  const float* b_qkv = (const float*)d_in[2];
  const float* w_out = (const float*)d_in[3];
  const float* b_out = (const float*)d_in[4];
  float* out = (float*)d_out;

  char* ws = (char*)d_ws;
  __bf16* xb    = (__bf16*)(ws);              // [4096][768]
  __bf16* wqkvT = (__bf16*)(ws + 6291456);    // [2304][768]
  __bf16* woT   = (__bf16*)(ws + 9830400);    // [768][768]
  __bf16* qb    = (__bf16*)(ws + 11010048);   // [B,H,T,64]  (pre-scaled by 0.125*log2e)
  __bf16* kb    = (__bf16*)(ws + 17301504);   // [B,H,T,64]
  __bf16* vtb   = (__bf16*)(ws + 23592960);   // [B,H,64,T]  (V transposed)
  __bf16* yatt  = (__bf16*)(ws + 29884416);   // [4096][768]

  cvt_bf16_kernel<<<3072, 256, 0, stream>>>(x, xb, 786432);
  cvtT_bf16_kernel<<<dim3(72, 24), 256, 0, stream>>>(w_qkv, wqkvT, 768, 2304);
  cvtT_bf16_kernel<<<dim3(24, 24), 256, 0, stream>>>(w_out, woT, 768, 768);
  // QKV: 128x144 tiles -> 32 x 16 = 512 blocks = EXACTLY 2/CU (co-resident pair
  // covers each other's stage drain). 6 waves, 2-buffer simple-sync, 68KB LDS.
  // XCD map: NNX=2 -> each XCD owns 2 n-slices (B slice 442KB, L2-resident).
  gemm_tn_kernel<0, 128, 144, 6, 2, 3, 2><<<512, 384, 0, stream>>>(
      xb, wqkvT, b_qkv, nullptr, qb, kb, vtb, 4096, 2304, 768, 16, 2, 32);
  attn_kernel<<<768, 256, 0, stream>>>(qb, kb, vtb, yatt);
  // out-proj: 64x96 tiles, 512 blocks (2/CU), 3-buf counted; XCD rect 16x4
  gemm_tn_kernel<1, 64, 96, 4, 2, 2, 3><<<512, 256, 0, stream>>>(
      yatt, woT, b_out, out, nullptr, nullptr, nullptr, 4096, 768, 768, 8, 4, 16);
}

// Round 16
// 116.662 us; speedup vs baseline: 1.0118x; 1.0118x over previous
//
#include <hip/hip_runtime.h>
#include <math.h>

// B=2, T=2048, D=768, H=12, HD=64
typedef __attribute__((ext_vector_type(8))) __bf16 bf16x8;
typedef __attribute__((ext_vector_type(4))) __bf16 bf16x4;
typedef __attribute__((ext_vector_type(4))) float f32x4;

#define GLOAD_LDS16(gsrc, ldst) \
  __builtin_amdgcn_global_load_lds((__attribute__((address_space(1))) const void*)(gsrc), \
                                   (__attribute__((address_space(3))) void*)(ldst), 16, 0, 0)

__device__ __forceinline__ float fexp2(float x) {
#if __has_builtin(__builtin_amdgcn_exp2f)
  return __builtin_amdgcn_exp2f(x);
#else
  return exp2f(x);
#endif
}

__global__ void cvt_bf16_kernel(const float* __restrict__ in, __bf16* __restrict__ out, int n4) {
  int i = blockIdx.x * 256 + threadIdx.x;
  if (i < n4) {
    float4 f = ((const float4*)in)[i];
    bf16x4 o;
    o[0] = (__bf16)f.x; o[1] = (__bf16)f.y; o[2] = (__bf16)f.z; o[3] = (__bf16)f.w;
    ((bf16x4*)out)[i] = o;
  }
}

// Tiled transpose-convert: out[C][R] = (bf16) in[R][C]. 32x32 tiles via LDS.
__global__ __launch_bounds__(256)
void cvtT_bf16_kernel(const float* __restrict__ in, __bf16* __restrict__ out, int R, int C) {
  __shared__ float t[32][33];
  int c0 = blockIdx.x * 32, r0 = blockIdx.y * 32;
  int tc = threadIdx.x & 31, tr = threadIdx.x >> 5;
#pragma unroll
  for (int i = 0; i < 4; ++i)
    t[tr + 8 * i][tc] = in[(size_t)(r0 + tr + 8 * i) * C + c0 + tc];
  __syncthreads();
#pragma unroll
  for (int i = 0; i < 4; ++i)
    out[(size_t)(c0 + tr + 8 * i) * R + r0 + tc] = (__bf16)t[tc][tr + 8 * i];
}

// TN GEMM: C[M][N] = A[M][K] * B[N][K]^T (+bias). BMxBN tile, BK=64, WAVES waves.
// BUFS=3: counted-vmcnt distance-2 pipeline (R14-validated: QKV 128x288 @ 256
// blocks = exactly 1/CU single round, 41.9us). BUFS=2: simple-sync dbuf.
template<int EPI, int BM, int BN, int WAVES, int WGM, int WGN, int BUFS>
__global__ __launch_bounds__(WAVES * 64, 3)
void gemm_tn_kernel(const __bf16* __restrict__ A, const __bf16* __restrict__ Bm,
                    const float* __restrict__ bias, float* __restrict__ outF,
                    __bf16* __restrict__ qo, __bf16* __restrict__ ko, __bf16* __restrict__ vo,
                    int M, int N, int K, int NBX, int NNX, int PPX) {
  constexpr int NTA = BM / 16, NTB = BN / 16;
  constexpr int NA = 2 * NTA;               // A segments (2 k-halves)
  constexpr int NSEG = 2 * NTA + 2 * NTB;   // 1KB segments per K-step
  constexpr int LPTH = (NSEG + WAVES - 1) / WAVES;
  constexpr int LPTR = NSEG % WAVES;        // waves < LPTR stage LPTH, rest LPTH-1
  constexpr int LLO = (LPTR == 0) ? LPTH : LPTH - 1;
  constexpr int AM = NTA / WGM;
  constexpr int BNF = NTB / WGN;
  const int lane = threadIdx.x & 63;
  const int wave = threadIdx.x >> 6;
  const int r16 = lane & 15, g = lane >> 4;
  const int id = blockIdx.x;
  const int xcd = id & 7, slot = id >> 3;
  const int nxn = NBX / NNX;
  const int mg = xcd / nxn, ng = xcd % nxn;
  const int lp = slot / NNX, ln = slot - (slot / NNX) * NNX;
  const int mBase = (mg * PPX + lp) * BM, nBase = (ng * NNX + ln) * BN;
  __shared__ __align__(16) __bf16 lds[BUFS][NSEG * 512];

  f32x4 acc[AM][BNF];
#pragma unroll
  for (int i = 0; i < AM; ++i)
#pragma unroll
    for (int j = 0; j < BNF; ++j) acc[i][j] = (f32x4){0.f, 0.f, 0.f, 0.f};

  const int mw = (wave / WGN) * AM;
  const int nw = (wave % WGN) * BNF;

  auto stage = [&](int ke, int b) {
#pragma unroll
    for (int i = 0; i < LPTH; ++i) {
      int s = wave + i * WAVES;             // interleaved; guard is wave-uniform
      if (LPTR == 0 || s < NSEG) {
        int isB = (s >= NA);
        int sb = isB ? s - NA : s;
        int nt = isB ? NTB : NTA;
        int ks = sb / nt, t8 = sb - ks * nt;
        int row = (isB ? nBase : mBase) + t8 * 16 + r16;
        const __bf16* src = (isB ? Bm : A) + (size_t)row * K + ke + ks * 32 + g * 8;
        GLOAD_LDS16(src, &lds[b][s * 512]);
      }
    }
  };

  auto mfma_step = [&](const __bf16* L) {
#pragma unroll
    for (int ks = 0; ks < 2; ++ks) {
      bf16x8 af[AM], bfr[BNF];
#pragma unroll
      for (int i = 0; i < AM; ++i)
        af[i] = *(const bf16x8*)&L[((ks * NTA + mw + i) * 64 + lane) * 8];
#pragma unroll
      for (int j = 0; j < BNF; ++j)
        bfr[j] = *(const bf16x8*)&L[((NA + ks * NTB + nw + j) * 64 + lane) * 8];
      __builtin_amdgcn_s_setprio(1);
#pragma unroll
      for (int i = 0; i < AM; ++i)
#pragma unroll
        for (int j = 0; j < BNF; ++j)
          acc[i][j] = __builtin_amdgcn_mfma_f32_16x16x32_bf16(af[i], bfr[j], acc[i][j], 0, 0, 0);
      __builtin_amdgcn_s_setprio(0);
    }
  };

  const int nt = K >> 6;
  if constexpr (BUFS == 2) {
    stage(0, 0);
    int cur = 0;
    for (int t = 0; t < nt; ++t) {
      __syncthreads();
      if (t + 1 < nt) stage((t + 1) << 6, cur ^ 1);
      mfma_step(lds[cur]);
      cur ^= 1;
    }
  } else {
    stage(0, 0);
    stage(64, 1);
    int cur = 0;
    for (int t = 0; t < nt; ++t) {
      if (t + 1 < nt) {
        if (LPTR != 0 && wave < LPTR) asm volatile("s_waitcnt vmcnt(%0)" :: "i"(LPTH) : "memory");
        else                          asm volatile("s_waitcnt vmcnt(%0)" :: "i"(LLO) : "memory");
      } else {
        asm volatile("s_waitcnt vmcnt(0)" ::: "memory");
      }
      __builtin_amdgcn_sched_barrier(0);
      __builtin_amdgcn_s_barrier();
      __builtin_amdgcn_sched_barrier(0);
      int nxt = cur + 2; if (nxt >= 3) nxt -= 3;
      if (t + 2 < nt) stage((t + 2) << 6, nxt);
      mfma_step(lds[cur]);
      if (++cur == 3) cur = 0;
    }
  }

#pragma unroll
  for (int i = 0; i < AM; ++i) {
#pragma unroll
    for (int j = 0; j < BNF; ++j) {
      int c = nBase + (nw + j) * 16 + r16;
      float bb = bias[c];
#pragma unroll
      for (int e = 0; e < 4; ++e) {
        int r = mBase + (mw + i) * 16 + g * 4 + e;
        float val = acc[i][j][e] + bb;
        if (EPI == 0) {
          int which = c / 768;             // 0:q 1:k 2:v
          int cc = c - which * 768;
          int hh = cc >> 6, dd = cc & 63;
          int bI = r >> 11, tt = r & 2047;
          if (which == 0) {
            // fold 1/sqrt(64) * log2(e) into q (softmax runs in exp2 space)
            qo[(((size_t)(bI * 12 + hh)) * 2048 + tt) * 64 + dd] = (__bf16)(val * 0.180336880f);
          } else if (which == 1) {
            ko[(((size_t)(bI * 12 + hh)) * 2048 + tt) * 64 + dd] = (__bf16)val;
          } else {
            vo[(((size_t)(bI * 12 + hh)) * 64 + dd) * 2048 + tt] = (__bf16)val;  // V^T [B,H,64,T]
          }
        } else {
          outF[(size_t)r * N + c] = val;
        }
      }
    }
  }
}

// Flash attention, causal, swapped-QK^T, O^T accumulation, 32q-PER-WAVE.
// R15 post-mortem: attn is LDS-THROUGHPUT-bound (pipe-cycle sum == duration).
// Fix: each wave owns 32 q-rows (2x 16-row subtiles) -> kf/vf fragment reads
// amortized over 2x the MFMAs (LDS cycles per FLOP ~x0.6).
// Block = 4 waves = 2 causal pairs: waves 0,1 = p-tiles (63-2u, 62-2u, Kt=32-u),
// waves 2,3 = a-tiles (2u, 2u+1, Kt=u+1). Grid 384 = 24 heads x 16 u.
// Untracked softmax (bounded scores, exp2 space).
__global__ __launch_bounds__(256, 3)
void attn_kernel(const __bf16* __restrict__ qg, const __bf16* __restrict__ kg,
                 const __bf16* __restrict__ vtg, __bf16* __restrict__ yatt) {
  const int id = blockIdx.x;
  const int chunk = id & 7, within = id >> 3;   // XCD chunk = 3 heads (L2-resident K/V)
  const int bh = chunk * 3 + (within >> 4);
  const int u = within & 15;
  const int lane = threadIdx.x & 63, wave = threadIdx.x >> 6;  // wave 0..3
  const int r16 = lane & 15, g = lane >> 4;
  const int bI = bh / 12, h = bh - bI * 12;
  const size_t headoff = (size_t)bh * 2048 * 64;
  const __bf16* Q = qg + headoff;
  const __bf16* Kh = kg + headoff;
  const __bf16* VT = vtg + headoff;             // [64][2048]

  __shared__ __align__(16) __bf16 Kbuf[2][4096];   // [64 k-rows][8 chunks] swizzled
  __shared__ __align__(16) __bf16 Vbuf[2][4096];   // [64 d-rows][8 chunks] swizzled
  __shared__ __align__(16) __bf16 Plds[4][16][72]; // per-wave strip (subs sequential)

  // wave -> 32-row tile
  const int myTile = (wave == 0) ? (63 - 2 * u) : (wave == 1) ? (62 - 2 * u)
                   : (wave == 2) ? (2 * u)      : (2 * u + 1);
  const int myKt = (myTile >> 1) + 1;
  const int Kmax = 32 - u;                      // p-tiles' Kt (block iteration count)

  const int row0 = myTile * 32 + r16;           // sub0 q-row for this lane
  const int row1 = myTile * 32 + 16 + r16;      // sub1

  bf16x8 qf[2][2];                              // [sub][ks]
#pragma unroll
  for (int ks = 0; ks < 2; ++ks) {
    qf[0][ks] = *(const bf16x8*)&Q[(size_t)row0 * 64 + ks * 32 + g * 8];
    qf[1][ks] = *(const bf16x8*)&Q[(size_t)row1 * 64 + ks * 32 + g * 8];
  }

  int srow[2], scl[2];
#pragma unroll
  for (int i = 0; i < 2; ++i) {
    int c = (i * 4 + wave) * 64 + lane;
    srow[i] = c >> 3;
    scl[i] = (c & 7) ^ (srow[i] & 7);
  }
  auto stage = [&](int kt, int b) {
#pragma unroll
    for (int i = 0; i < 2; ++i) {
      GLOAD_LDS16(&Kh[(size_t)(kt * 64 + srow[i]) * 64 + scl[i] * 8], &Kbuf[b][(i * 4 + wave) * 512]);
      GLOAD_LDS16(&VT[(size_t)srow[i] * 2048 + kt * 64 + scl[i] * 8], &Vbuf[b][(i * 4 + wave) * 512]);
    }
  };

  f32x4 o0[4], o1[4];
#pragma unroll
  for (int j = 0; j < 4; ++j) { o0[j] = (f32x4){0.f,0.f,0.f,0.f}; o1[j] = (f32x4){0.f,0.f,0.f,0.f}; }
  float l0 = 0.f, l1 = 0.f;

  stage(0, 0);
  for (int kt = 0; kt < Kmax; ++kt) {
    const int cur = kt & 1;
    __syncthreads();                     // drains stage(cur); guards buffer reuse
    if (kt + 1 < Kmax) stage(kt + 1, cur ^ 1);
    if (kt < myKt) {
      // QK^T both subs, kf read ONCE per fragment (the LDS-traffic lever)
      f32x4 st0[4], st1[4];
#pragma unroll
      for (int j = 0; j < 4; ++j) { st0[j] = (f32x4){0.f,0.f,0.f,0.f}; st1[j] = (f32x4){0.f,0.f,0.f,0.f}; }
      __builtin_amdgcn_s_setprio(1);
#pragma unroll
      for (int ks = 0; ks < 2; ++ks)
#pragma unroll
        for (int j = 0; j < 4; ++j) {
          int row = j * 16 + r16;
          int cp = (ks * 4 + g) ^ (row & 7);
          bf16x8 kf = *(const bf16x8*)&Kbuf[cur][(row * 8 + cp) * 8];
          st0[j] = __builtin_amdgcn_mfma_f32_16x16x32_bf16(kf, qf[0][ks], st0[j], 0, 0, 0);
          st1[j] = __builtin_amdgcn_mfma_f32_16x16x32_bf16(kf, qf[1][ks], st1[j], 0, 0, 0);
        }
      __builtin_amdgcn_s_setprio(0);
      // V fragments (shared by both subs), in flight under softmax
      bf16x8 vf[2][4];
#pragma unroll
      for (int ks = 0; ks < 2; ++ks)
#pragma unroll
        for (int dj = 0; dj < 4; ++dj) {
          int row = dj * 16 + r16;
          int cp = (ks * 4 + g) ^ (row & 7);
          vf[ks][dj] = *(const bf16x8*)&Vbuf[cur][(row * 8 + cp) * 8];
        }
      const bool lastT = (kt == myKt - 1);
      if (lastT) {   // causal: k = kt*64 + j*16 + 4g+e vs own q-row (per sub)
#pragma unroll
        for (int j = 0; j < 4; ++j)
#pragma unroll
          for (int e = 0; e < 4; ++e) {
            int k = kt * 64 + j * 16 + 4 * g + e;
            if (k > row0) st0[j][e] = -INFINITY;
            if (k > row1) st1[j][e] = -INFINITY;
          }
      }
      // untracked softmax, interleaved sub chains (exp2(-inf)=0 handles masking)
      float ls0 = 0.f, ls1 = 0.f;
#pragma unroll
      for (int j = 0; j < 4; ++j)
#pragma unroll
        for (int e = 0; e < 4; ++e) {
          float p0 = fexp2(st0[j][e]);
          float p1 = fexp2(st1[j][e]);
          st0[j][e] = p0; ls0 += p0;
          st1[j][e] = p1; ls1 += p1;
        }
      ls0 += __shfl_xor(ls0, 16, 64); ls0 += __shfl_xor(ls0, 32, 64); l0 += ls0;
      ls1 += __shfl_xor(ls1, 16, 64); ls1 += __shfl_xor(ls1, 32, 64); l1 += ls1;
      // sub0: P -> LDS strip, PV
#pragma unroll
      for (int j = 0; j < 4; ++j) {
        bf16x4 pk;
#pragma unroll
        for (int e = 0; e < 4; ++e) pk[e] = (__bf16)st0[j][e];
        *(bf16x4*)&Plds[wave][r16][j * 16 + 4 * g] = pk;
      }
      __builtin_amdgcn_s_setprio(1);
#pragma unroll
      for (int ks = 0; ks < 2; ++ks) {
        bf16x8 pf = *(const bf16x8*)&Plds[wave][r16][ks * 32 + g * 8];
#pragma unroll
        for (int dj = 0; dj < 4; ++dj)
          o0[dj] = __builtin_amdgcn_mfma_f32_16x16x32_bf16(vf[ks][dj], pf, o0[dj], 0, 0, 0);
      }
      __builtin_amdgcn_s_setprio(0);
      // sub1: strip reused (same-wave DS ops are in-order; RAW/WAR safe)
#pragma unroll
      for (int j = 0; j < 4; ++j) {
        bf16x4 pk;
#pragma unroll
        for (int e = 0; e < 4; ++e) pk[e] = (__bf16)st1[j][e];
        *(bf16x4*)&Plds[wave][r16][j * 16 + 4 * g] = pk;
      }
      __builtin_amdgcn_s_setprio(1);
#pragma unroll
      for (int ks = 0; ks < 2; ++ks) {
        bf16x8 pf = *(const bf16x8*)&Plds[wave][r16][ks * 32 + g * 8];
#pragma unroll
        for (int dj = 0; dj < 4; ++dj)
          o1[dj] = __builtin_amdgcn_mfma_f32_16x16x32_bf16(vf[ks][dj], pf, o1[dj], 0, 0, 0);
      }
      __builtin_amdgcn_s_setprio(0);
    }
  }

  // epilogue: O^T[d][q], per-lane q = r16; d = dj*16 + 4g + e (4 contiguous)
  float inv0 = 1.0f / l0, inv1 = 1.0f / l1;
#pragma unroll
  for (int dj = 0; dj < 4; ++dj) {
    bf16x4 ov0, ov1;
#pragma unroll
    for (int e = 0; e < 4; ++e) { ov0[e] = (__bf16)(o0[dj][e] * inv0); ov1[e] = (__bf16)(o1[dj][e] * inv1); }
    *(bf16x4*)&yatt[((size_t)(bI * 2048 + row0)) * 768 + h * 64 + dj * 16 + 4 * g] = ov0;
    *(bf16x4*)&yatt[((size_t)(bI * 2048 + row1)) * 768 + h * 64 + dj * 16 + 4 * g] = ov1;
  }
}

extern "C" void kernel_launch(void* const* d_in, const int* in_sizes, int n_in,
                              void* d_out, int out_size, void* d_ws, size_t ws_size,
                              hipStream_t stream) {
  (void)in_sizes; (void)n_in; (void)out_size; (void)ws_size;
  const float* x     = (const float*)d_in[0];
  const float* w_qkv = (const float*)d_in[1];
  const float* b_qkv = (const float*)d_in[2];
  const float* w_out = (const float*)d_in[3];
  const float* b_out = (const float*)d_in[4];
  float* out = (float*)d_out;

  char* ws = (char*)d_ws;
  __bf16* xb    = (__bf16*)(ws);              // [4096][768]
  __bf16* wqkvT = (__bf16*)(ws + 6291456);    // [2304][768]
  __bf16* woT   = (__bf16*)(ws + 9830400);    // [768][768]
  __bf16* qb    = (__bf16*)(ws + 11010048);   // [B,H,T,64]  (pre-scaled by 0.125*log2e)
  __bf16* kb    = (__bf16*)(ws + 17301504);   // [B,H,T,64]
  __bf16* vtb   = (__bf16*)(ws + 23592960);   // [B,H,64,T]  (V transposed)
  __bf16* yatt  = (__bf16*)(ws + 29884416);   // [4096][768]

  cvt_bf16_kernel<<<3072, 256, 0, stream>>>(x, xb, 786432);
  cvtT_bf16_kernel<<<dim3(72, 24), 256, 0, stream>>>(w_qkv, wqkvT, 768, 2304);
  cvtT_bf16_kernel<<<dim3(24, 24), 256, 0, stream>>>(w_out, woT, 768, 768);
  // QKV: R14 config (best measured): 128x288, 12 waves, 3-buf counted-vmcnt,
  // 256 blocks = exactly 1/CU; XCD owns one 288-col B-slice (L2-resident).
  gemm_tn_kernel<0, 128, 288, 12, 2, 6, 3><<<256, 768, 0, stream>>>(
      xb, wqkvT, b_qkv, nullptr, qb, kb, vtb, 4096, 2304, 768, 8, 1, 32);
  // attn: 32q/wave, 2 pairs per 4-wave block, 384 blocks
  attn_kernel<<<384, 256, 0, stream>>>(qb, kb, vtb, yatt);
  // out-proj: 64x96 tiles, 512 blocks (2/CU), 3-buf counted; XCD rect 16x4
  gemm_tn_kernel<1, 64, 96, 4, 2, 2, 3><<<512, 256, 0, stream>>>(
      yatt, woT, b_out, out, nullptr, nullptr, nullptr, 4096, 768, 768, 8, 4, 16);
}

// Round 17
// 116.516 us; speedup vs baseline: 1.0130x; 1.0012x over previous
//
#include <hip/hip_runtime.h>
#include <math.h>

// B=2, T=2048, D=768, H=12, HD=64
typedef __attribute__((ext_vector_type(8))) __bf16 bf16x8;
typedef __attribute__((ext_vector_type(4))) __bf16 bf16x4;
typedef __attribute__((ext_vector_type(4))) float f32x4;

#define GLOAD_LDS16(gsrc, ldst) \
  __builtin_amdgcn_global_load_lds((__attribute__((address_space(1))) const void*)(gsrc), \
                                   (__attribute__((address_space(3))) void*)(ldst), 16, 0, 0)

__device__ __forceinline__ float fexp2(float x) {
#if __has_builtin(__builtin_amdgcn_exp2f)
  return __builtin_amdgcn_exp2f(x);
#else
  return exp2f(x);
#endif
}

__global__ void cvt_bf16_kernel(const float* __restrict__ in, __bf16* __restrict__ out, int n4) {
  int i = blockIdx.x * 256 + threadIdx.x;
  if (i < n4) {
    float4 f = ((const float4*)in)[i];
    bf16x4 o;
    o[0] = (__bf16)f.x; o[1] = (__bf16)f.y; o[2] = (__bf16)f.z; o[3] = (__bf16)f.w;
    ((bf16x4*)out)[i] = o;
  }
}

// Tiled transpose-convert: out[C][R] = (bf16) in[R][C]. 32x32 tiles via LDS.
__global__ __launch_bounds__(256)
void cvtT_bf16_kernel(const float* __restrict__ in, __bf16* __restrict__ out, int R, int C) {
  __shared__ float t[32][33];
  int c0 = blockIdx.x * 32, r0 = blockIdx.y * 32;
  int tc = threadIdx.x & 31, tr = threadIdx.x >> 5;
#pragma unroll
  for (int i = 0; i < 4; ++i)
    t[tr + 8 * i][tc] = in[(size_t)(r0 + tr + 8 * i) * C + c0 + tc];
  __syncthreads();
#pragma unroll
  for (int i = 0; i < 4; ++i)
    out[(size_t)(c0 + tr + 8 * i) * R + r0 + tc] = (__bf16)t[tc][tr + 8 * i];
}

// TN GEMM: C[M][N] = A[M][K] * B[N][K]^T (+bias). BMxBN tile, BK=64, WAVES waves.
// BUFS=3: counted-vmcnt distance-2 pipeline (R14-validated). BUFS=2: simple dbuf.
template<int EPI, int BM, int BN, int WAVES, int WGM, int WGN, int BUFS>
__global__ __launch_bounds__(WAVES * 64, 3)
void gemm_tn_kernel(const __bf16* __restrict__ A, const __bf16* __restrict__ Bm,
                    const float* __restrict__ bias, float* __restrict__ outF,
                    __bf16* __restrict__ qo, __bf16* __restrict__ ko, __bf16* __restrict__ vo,
                    int M, int N, int K, int NBX, int NNX, int PPX) {
  constexpr int NTA = BM / 16, NTB = BN / 16;
  constexpr int NA = 2 * NTA;               // A segments (2 k-halves)
  constexpr int NSEG = 2 * NTA + 2 * NTB;   // 1KB segments per K-step
  constexpr int LPTH = (NSEG + WAVES - 1) / WAVES;
  constexpr int LPTR = NSEG % WAVES;        // waves < LPTR stage LPTH, rest LPTH-1
  constexpr int LLO = (LPTR == 0) ? LPTH : LPTH - 1;
  constexpr int AM = NTA / WGM;
  constexpr int BNF = NTB / WGN;
  const int lane = threadIdx.x & 63;
  const int wave = threadIdx.x >> 6;
  const int r16 = lane & 15, g = lane >> 4;
  const int id = blockIdx.x;
  const int xcd = id & 7, slot = id >> 3;
  const int nxn = NBX / NNX;
  const int mg = xcd / nxn, ng = xcd % nxn;
  const int lp = slot / NNX, ln = slot - (slot / NNX) * NNX;
  const int mBase = (mg * PPX + lp) * BM, nBase = (ng * NNX + ln) * BN;
  __shared__ __align__(16) __bf16 lds[BUFS][NSEG * 512];

  f32x4 acc[AM][BNF];
#pragma unroll
  for (int i = 0; i < AM; ++i)
#pragma unroll
    for (int j = 0; j < BNF; ++j) acc[i][j] = (f32x4){0.f, 0.f, 0.f, 0.f};

  const int mw = (wave / WGN) * AM;
  const int nw = (wave % WGN) * BNF;

  auto stage = [&](int ke, int b) {
#pragma unroll
    for (int i = 0; i < LPTH; ++i) {
      int s = wave + i * WAVES;             // interleaved; guard is wave-uniform
      if (LPTR == 0 || s < NSEG) {
        int isB = (s >= NA);
        int sb = isB ? s - NA : s;
        int nt = isB ? NTB : NTA;
        int ks = sb / nt, t8 = sb - ks * nt;
        int row = (isB ? nBase : mBase) + t8 * 16 + r16;
        const __bf16* src = (isB ? Bm : A) + (size_t)row * K + ke + ks * 32 + g * 8;
        GLOAD_LDS16(src, &lds[b][s * 512]);
      }
    }
  };

  auto mfma_step = [&](const __bf16* L) {
#pragma unroll
    for (int ks = 0; ks < 2; ++ks) {
      bf16x8 af[AM], bfr[BNF];
#pragma unroll
      for (int i = 0; i < AM; ++i)
        af[i] = *(const bf16x8*)&L[((ks * NTA + mw + i) * 64 + lane) * 8];
#pragma unroll
      for (int j = 0; j < BNF; ++j)
        bfr[j] = *(const bf16x8*)&L[((NA + ks * NTB + nw + j) * 64 + lane) * 8];
      __builtin_amdgcn_s_setprio(1);
#pragma unroll
      for (int i = 0; i < AM; ++i)
#pragma unroll
        for (int j = 0; j < BNF; ++j)
          acc[i][j] = __builtin_amdgcn_mfma_f32_16x16x32_bf16(af[i], bfr[j], acc[i][j], 0, 0, 0);
      __builtin_amdgcn_s_setprio(0);
    }
  };

  const int nt = K >> 6;
  if constexpr (BUFS == 2) {
    stage(0, 0);
    int cur = 0;
    for (int t = 0; t < nt; ++t) {
      __syncthreads();
      if (t + 1 < nt) stage((t + 1) << 6, cur ^ 1);
      mfma_step(lds[cur]);
      cur ^= 1;
    }
  } else {
    stage(0, 0);
    stage(64, 1);
    int cur = 0;
    for (int t = 0; t < nt; ++t) {
      if (t + 1 < nt) {
        if (LPTR != 0 && wave < LPTR) asm volatile("s_waitcnt vmcnt(%0)" :: "i"(LPTH) : "memory");
        else                          asm volatile("s_waitcnt vmcnt(%0)" :: "i"(LLO) : "memory");
      } else {
        asm volatile("s_waitcnt vmcnt(0)" ::: "memory");
      }
      __builtin_amdgcn_sched_barrier(0);
      __builtin_amdgcn_s_barrier();
      __builtin_amdgcn_sched_barrier(0);
      int nxt = cur + 2; if (nxt >= 3) nxt -= 3;
      if (t + 2 < nt) stage((t + 2) << 6, nxt);
      mfma_step(lds[cur]);
      if (++cur == 3) cur = 0;
    }
  }

#pragma unroll
  for (int i = 0; i < AM; ++i) {
#pragma unroll
    for (int j = 0; j < BNF; ++j) {
      int c = nBase + (nw + j) * 16 + r16;
      float bb = bias[c];
#pragma unroll
      for (int e = 0; e < 4; ++e) {
        int r = mBase + (mw + i) * 16 + g * 4 + e;
        float val = acc[i][j][e] + bb;
        if (EPI == 0) {
          int which = c / 768;             // 0:q 1:k 2:v
          int cc = c - which * 768;
          int hh = cc >> 6, dd = cc & 63;
          int bI = r >> 11, tt = r & 2047;
          if (which == 0) {
            // fold 1/sqrt(64) * log2(e) into q (softmax runs in exp2 space)
            qo[(((size_t)(bI * 12 + hh)) * 2048 + tt) * 64 + dd] = (__bf16)(val * 0.180336880f);
          } else if (which == 1) {
            ko[(((size_t)(bI * 12 + hh)) * 2048 + tt) * 64 + dd] = (__bf16)val;
          } else {
            vo[(((size_t)(bI * 12 + hh)) * 64 + dd) * 2048 + tt] = (__bf16)val;  // V^T [B,H,64,T]
          }
        } else {
          outF[(size_t)r * N + c] = val;
        }
      }
    }
  }
}

// Flash attention, causal, swapped-QK^T, O^T accumulation.
// DUAL-SUB 4-wave blocks: block = TWO adjacent causal pairs; each wave owns one
// 16-row p-sub (tile 63-2u or 62-2u, Kt=32-u, active ALL iters) and one 16-row
// a-sub (tile 2u or 2u+1, Kt=u+1, active first u+1 iters). kf/vf fragment reads
// shared across the wave's two subs when both active (~0.7x LDS per sub-unit),
// and every wave is busy every iteration (R16's idle-wave flaw fixed).
// Grid 384 with u ascending = longest-first LPT packing per XCD chunk.
__global__ __launch_bounds__(256, 3)
void attn_kernel(const __bf16* __restrict__ qg, const __bf16* __restrict__ kg,
                 const __bf16* __restrict__ vtg, __bf16* __restrict__ yatt) {
  const int id = blockIdx.x;
  const int chunk = id & 7, within = id >> 3;   // 48 blocks per XCD chunk
  const int u = within / 3;                     // 0..15, ascending -> longest first
  const int bh = chunk * 3 + (within - u * 3);
  const int Kmax = 32 - u, Ka = u + 1;          // p-iters (block loop), a-iters
  const int lane = threadIdx.x & 63, wave = threadIdx.x >> 6;  // wave 0..3
  const int r16 = lane & 15, g = lane >> 4;
  const int bI = bh / 12, h = bh - bI * 12;
  const size_t headoff = (size_t)bh * 2048 * 64;
  const __bf16* Q = qg + headoff;
  const __bf16* Kh = kg + headoff;
  const __bf16* VT = vtg + headoff;             // [64][2048]

  __shared__ __align__(16) __bf16 Kbuf[2][4096];   // [64 k-rows][8 chunks] swizzled
  __shared__ __align__(16) __bf16 Vbuf[2][4096];   // [64 d-rows][8 chunks] swizzled
  __shared__ __align__(16) __bf16 Plds[4][16][72]; // per-wave strip (p/a sequential)

  const int ptile = 63 - 2 * u - (wave >> 1);   // waves 0,1 -> 63-2u; 2,3 -> 62-2u
  const int atile = 2 * u + (wave >> 1);        // waves 0,1 -> 2u;    2,3 -> 2u+1
  const int rowP = ptile * 32 + (wave & 1) * 16 + r16;
  const int rowA = atile * 32 + (wave & 1) * 16 + r16;

  bf16x8 qfp[2], qfa[2];
#pragma unroll
  for (int ks = 0; ks < 2; ++ks) {
    qfp[ks] = *(const bf16x8*)&Q[(size_t)rowP * 64 + ks * 32 + g * 8];
    qfa[ks] = *(const bf16x8*)&Q[(size_t)rowA * 64 + ks * 32 + g * 8];
  }

  int srow[2], scl[2];
#pragma unroll
  for (int i = 0; i < 2; ++i) {
    int c = (i * 4 + wave) * 64 + lane;
    srow[i] = c >> 3;
    scl[i] = (c & 7) ^ (srow[i] & 7);
  }
  auto stage = [&](int kt, int b) {
#pragma unroll
    for (int i = 0; i < 2; ++i) {
      GLOAD_LDS16(&Kh[(size_t)(kt * 64 + srow[i]) * 64 + scl[i] * 8], &Kbuf[b][(i * 4 + wave) * 512]);
      GLOAD_LDS16(&VT[(size_t)srow[i] * 2048 + kt * 64 + scl[i] * 8], &Vbuf[b][(i * 4 + wave) * 512]);
    }
  };

  f32x4 op[4], oa[4];
#pragma unroll
  for (int j = 0; j < 4; ++j) { op[j] = (f32x4){0.f,0.f,0.f,0.f}; oa[j] = (f32x4){0.f,0.f,0.f,0.f}; }
  float lp = 0.f, la = 0.f;

  stage(0, 0);
  for (int kt = 0; kt < Kmax; ++kt) {
    const int cur = kt & 1;
    __syncthreads();                     // drains stage(cur); guards buffer reuse
    if (kt + 1 < Kmax) stage(kt + 1, cur ^ 1);
    const bool dualA = (kt < Ka);
    // QK^T: kf read ONCE, feeds p-sub (always) and a-sub (when active)
    f32x4 stp[4], sta[4];
#pragma unroll
    for (int j = 0; j < 4; ++j) { stp[j] = (f32x4){0.f,0.f,0.f,0.f}; sta[j] = (f32x4){0.f,0.f,0.f,0.f}; }
    __builtin_amdgcn_s_setprio(1);
#pragma unroll
    for (int ks = 0; ks < 2; ++ks)
#pragma unroll
      for (int j = 0; j < 4; ++j) {
        int row = j * 16 + r16;
        int cp = (ks * 4 + g) ^ (row & 7);
        bf16x8 kf = *(const bf16x8*)&Kbuf[cur][(row * 8 + cp) * 8];
        stp[j] = __builtin_amdgcn_mfma_f32_16x16x32_bf16(kf, qfp[ks], stp[j], 0, 0, 0);
        if (dualA) sta[j] = __builtin_amdgcn_mfma_f32_16x16x32_bf16(kf, qfa[ks], sta[j], 0, 0, 0);
      }
    __builtin_amdgcn_s_setprio(0);
    // V fragments (shared by both subs), in flight under softmax
    bf16x8 vf[2][4];
#pragma unroll
    for (int ks = 0; ks < 2; ++ks)
#pragma unroll
      for (int dj = 0; dj < 4; ++dj) {
        int row = dj * 16 + r16;
        int cp = (ks * 4 + g) ^ (row & 7);
        vf[ks][dj] = *(const bf16x8*)&Vbuf[cur][(row * 8 + cp) * 8];
      }
    // causal masks: k = kt*64 + j*16 + 4g+e vs own q-row
    if (kt == Kmax - 1) {
#pragma unroll
      for (int j = 0; j < 4; ++j)
#pragma unroll
        for (int e = 0; e < 4; ++e)
          if (kt * 64 + j * 16 + 4 * g + e > rowP) stp[j][e] = -INFINITY;
    }
    if (dualA && kt == Ka - 1) {
#pragma unroll
      for (int j = 0; j < 4; ++j)
#pragma unroll
        for (int e = 0; e < 4; ++e)
          if (kt * 64 + j * 16 + 4 * g + e > rowA) sta[j][e] = -INFINITY;
    }
    // untracked softmax in exp2 space (bounded scores; exp2(-inf)=0 masks)
    float lsp = 0.f, lsa = 0.f;
#pragma unroll
    for (int j = 0; j < 4; ++j)
#pragma unroll
      for (int e = 0; e < 4; ++e) {
        float pv = fexp2(stp[j][e]);
        stp[j][e] = pv; lsp += pv;
        if (dualA) {
          float av = fexp2(sta[j][e]);
          sta[j][e] = av; lsa += av;
        }
      }
    lsp += __shfl_xor(lsp, 16, 64); lsp += __shfl_xor(lsp, 32, 64); lp += lsp;
    if (dualA) { lsa += __shfl_xor(lsa, 16, 64); lsa += __shfl_xor(lsa, 32, 64); la += lsa; }
    // p-sub: P -> strip, PV
#pragma unroll
    for (int j = 0; j < 4; ++j) {
      bf16x4 pk;
#pragma unroll
      for (int e = 0; e < 4; ++e) pk[e] = (__bf16)stp[j][e];
      *(bf16x4*)&Plds[wave][r16][j * 16 + 4 * g] = pk;
    }
    __builtin_amdgcn_s_setprio(1);
#pragma unroll
    for (int ks = 0; ks < 2; ++ks) {
      bf16x8 pf = *(const bf16x8*)&Plds[wave][r16][ks * 32 + g * 8];
#pragma unroll
      for (int dj = 0; dj < 4; ++dj)
        op[dj] = __builtin_amdgcn_mfma_f32_16x16x32_bf16(vf[ks][dj], pf, op[dj], 0, 0, 0);
    }
    __builtin_amdgcn_s_setprio(0);
    // a-sub: strip reused (same-wave DS ops in-order; RAW/WAR safe), vf still live
    if (dualA) {
#pragma unroll
      for (int j = 0; j < 4; ++j) {
        bf16x4 ak;
#pragma unroll
        for (int e = 0; e < 4; ++e) ak[e] = (__bf16)sta[j][e];
        *(bf16x4*)&Plds[wave][r16][j * 16 + 4 * g] = ak;
      }
      __builtin_amdgcn_s_setprio(1);
#pragma unroll
      for (int ks = 0; ks < 2; ++ks) {
        bf16x8 pf = *(const bf16x8*)&Plds[wave][r16][ks * 32 + g * 8];
#pragma unroll
        for (int dj = 0; dj < 4; ++dj)
          oa[dj] = __builtin_amdgcn_mfma_f32_16x16x32_bf16(vf[ks][dj], pf, oa[dj], 0, 0, 0);
      }
      __builtin_amdgcn_s_setprio(0);
    }
  }

  // epilogue: O^T[d][q], per-lane q = r16; d = dj*16 + 4g + e (4 contiguous)
  float invp = 1.0f / lp, inva = 1.0f / la;
#pragma unroll
  for (int dj = 0; dj < 4; ++dj) {
    bf16x4 ovp, ova;
#pragma unroll
    for (int e = 0; e < 4; ++e) { ovp[e] = (__bf16)(op[dj][e] * invp); ova[e] = (__bf16)(oa[dj][e] * inva); }
    *(bf16x4*)&yatt[((size_t)(bI * 2048 + rowP)) * 768 + h * 64 + dj * 16 + 4 * g] = ovp;
    *(bf16x4*)&yatt[((size_t)(bI * 2048 + rowA)) * 768 + h * 64 + dj * 16 + 4 * g] = ova;
  }
}

extern "C" void kernel_launch(void* const* d_in, const int* in_sizes, int n_in,
                              void* d_out, int out_size, void* d_ws, size_t ws_size,
                              hipStream_t stream) {
  (void)in_sizes; (void)n_in; (void)out_size; (void)ws_size;
  const float* x     = (const float*)d_in[0];
  const float* w_qkv = (const float*)d_in[1];
  const float* b_qkv = (const float*)d_in[2];
  const float* w_out = (const float*)d_in[3];
  const float* b_out = (const float*)d_in[4];
  float* out = (float*)d_out;

  char* ws = (char*)d_ws;
  __bf16* xb    = (__bf16*)(ws);              // [4096][768]
  __bf16* wqkvT = (__bf16*)(ws + 6291456);    // [2304][768]
  __bf16* woT   = (__bf16*)(ws + 9830400);    // [768][768]
  __bf16* qb    = (__bf16*)(ws + 11010048);   // [B,H,T,64]  (pre-scaled by 0.125*log2e)
  __bf16* kb    = (__bf16*)(ws + 17301504);   // [B,H,T,64]
  __bf16* vtb   = (__bf16*)(ws + 23592960);   // [B,H,64,T]  (V transposed)
  __bf16* yatt  = (__bf16*)(ws + 29884416);   // [4096][768]

  cvt_bf16_kernel<<<3072, 256, 0, stream>>>(x, xb, 786432);
  cvtT_bf16_kernel<<<dim3(72, 24), 256, 0, stream>>>(w_qkv, wqkvT, 768, 2304);
  cvtT_bf16_kernel<<<dim3(24, 24), 256, 0, stream>>>(w_out, woT, 768, 768);
  // QKV: R14 config (best measured 41.9us): 128x288, 12 waves, 3-buf counted,
  // 256 blocks = exactly 1/CU; each XCD owns one 288-col B-slice (L2-resident).
  gemm_tn_kernel<0, 128, 288, 12, 2, 6, 3><<<256, 768, 0, stream>>>(
      xb, wqkvT, b_qkv, nullptr, qb, kb, vtb, 4096, 2304, 768, 8, 1, 32);
  // attn: dual-sub 4-wave blocks, 384 blocks (longest-first in each XCD chunk)
  attn_kernel<<<384, 256, 0, stream>>>(qb, kb, vtb, yatt);
  // out-proj: 64x96 tiles, 512 blocks (2/CU), 3-buf counted; XCD rect 16x4
  gemm_tn_kernel<1, 64, 96, 4, 2, 2, 3><<<512, 256, 0, stream>>>(
      yatt, woT, b_out, out, nullptr, nullptr, nullptr, 4096, 768, 768, 8, 4, 16);
}

// Round 18
// 101.098 us; speedup vs baseline: 1.1675x; 1.1525x over previous
//
#include <hip/hip_runtime.h>
#include <math.h>

// B=2, T=2048, D=768, H=12, HD=64
typedef __attribute__((ext_vector_type(8))) __bf16 bf16x8;
typedef __attribute__((ext_vector_type(4))) __bf16 bf16x4;
typedef __attribute__((ext_vector_type(4))) float f32x4;

#define GLOAD_LDS16(gsrc, ldst) \
  __builtin_amdgcn_global_load_lds((__attribute__((address_space(1))) const void*)(gsrc), \
                                   (__attribute__((address_space(3))) void*)(ldst), 16, 0, 0)

__device__ __forceinline__ float fexp2(float x) {
#if __has_builtin(__builtin_amdgcn_exp2f)
  return __builtin_amdgcn_exp2f(x);
#else
  return exp2f(x);
#endif
}

// Fused conversion kernel: one launch does all three input preps.
//  bid <  3072          : x fp32 -> bf16 flat (float4 per thread)
//  3072 <= bid < 4800   : w_qkv^T 32x32 tile transpose-convert (768x2304)
//  bid >= 4800          : w_out^T 32x32 tile transpose-convert (768x768)
__global__ __launch_bounds__(256)
void cvt_fused_kernel(const float* __restrict__ x, __bf16* __restrict__ xb,
                      const float* __restrict__ wqkv, __bf16* __restrict__ wqkvT,
                      const float* __restrict__ wout, __bf16* __restrict__ woT) {
  __shared__ float t[32][33];
  const int bid = blockIdx.x;
  if (bid < 3072) {
    int i = bid * 256 + threadIdx.x;   // 786432 float4s
    float4 f = ((const float4*)x)[i];
    bf16x4 o;
    o[0] = (__bf16)f.x; o[1] = (__bf16)f.y; o[2] = (__bf16)f.z; o[3] = (__bf16)f.w;
    ((bf16x4*)xb)[i] = o;
    return;
  }
  const float* in;
  __bf16* out;
  int R, C, bx, by;
  if (bid < 4800) {
    int tt = bid - 3072;               // 72 x 24 tiles
    bx = tt % 72; by = tt / 72;
    in = wqkv; out = wqkvT; R = 768; C = 2304;
  } else {
    int tt = bid - 4800;               // 24 x 24 tiles
    bx = tt % 24; by = tt / 24;
    in = wout; out = woT; R = 768; C = 768;
  }
  int c0 = bx * 32, r0 = by * 32;
  int tc = threadIdx.x & 31, tr = threadIdx.x >> 5;
#pragma unroll
  for (int i = 0; i < 4; ++i)
    t[tr + 8 * i][tc] = in[(size_t)(r0 + tr + 8 * i) * C + c0 + tc];
  __syncthreads();
#pragma unroll
  for (int i = 0; i < 4; ++i)
    out[(size_t)(c0 + tr + 8 * i) * R + r0 + tc] = (__bf16)t[tc][tr + 8 * i];
}

// TN GEMM: C[M][N] = A[M][K] * B[N][K]^T (+bias). BMxBN tile, BK=64, WAVES waves.
// BUFS=3: counted-vmcnt distance-2 pipeline (R14-validated). BUFS=2: simple dbuf.
template<int EPI, int BM, int BN, int WAVES, int WGM, int WGN, int BUFS>
__global__ __launch_bounds__(WAVES * 64, 3)
void gemm_tn_kernel(const __bf16* __restrict__ A, const __bf16* __restrict__ Bm,
                    const float* __restrict__ bias, float* __restrict__ outF,
                    __bf16* __restrict__ qo, __bf16* __restrict__ ko, __bf16* __restrict__ vo,
                    int M, int N, int K, int NBX, int NNX, int PPX) {
  constexpr int NTA = BM / 16, NTB = BN / 16;
  constexpr int NA = 2 * NTA;               // A segments (2 k-halves)
  constexpr int NSEG = 2 * NTA + 2 * NTB;   // 1KB segments per K-step
  constexpr int LPTH = (NSEG + WAVES - 1) / WAVES;
  constexpr int LPTR = NSEG % WAVES;        // waves < LPTR stage LPTH, rest LPTH-1
  constexpr int LLO = (LPTR == 0) ? LPTH : LPTH - 1;
  constexpr int AM = NTA / WGM;
  constexpr int BNF = NTB / WGN;
  const int lane = threadIdx.x & 63;
  const int wave = threadIdx.x >> 6;
  const int r16 = lane & 15, g = lane >> 4;
  const int id = blockIdx.x;
  const int xcd = id & 7, slot = id >> 3;
  const int nxn = NBX / NNX;
  const int mg = xcd / nxn, ng = xcd % nxn;
  const int lp = slot / NNX, ln = slot - (slot / NNX) * NNX;
  const int mBase = (mg * PPX + lp) * BM, nBase = (ng * NNX + ln) * BN;
  __shared__ __align__(16) __bf16 lds[BUFS][NSEG * 512];

  f32x4 acc[AM][BNF];
#pragma unroll
  for (int i = 0; i < AM; ++i)
#pragma unroll
    for (int j = 0; j < BNF; ++j) acc[i][j] = (f32x4){0.f, 0.f, 0.f, 0.f};

  const int mw = (wave / WGN) * AM;
  const int nw = (wave % WGN) * BNF;

  auto stage = [&](int ke, int b) {
#pragma unroll
    for (int i = 0; i < LPTH; ++i) {
      int s = wave + i * WAVES;             // interleaved; guard is wave-uniform
      if (LPTR == 0 || s < NSEG) {
        int isB = (s >= NA);
        int sb = isB ? s - NA : s;
        int nt = isB ? NTB : NTA;
        int ks = sb / nt, t8 = sb - ks * nt;
        int row = (isB ? nBase : mBase) + t8 * 16 + r16;
        const __bf16* src = (isB ? Bm : A) + (size_t)row * K + ke + ks * 32 + g * 8;
        GLOAD_LDS16(src, &lds[b][s * 512]);
      }
    }
  };

  auto mfma_step = [&](const __bf16* L) {
#pragma unroll
    for (int ks = 0; ks < 2; ++ks) {
      bf16x8 af[AM], bfr[BNF];
#pragma unroll
      for (int i = 0; i < AM; ++i)
        af[i] = *(const bf16x8*)&L[((ks * NTA + mw + i) * 64 + lane) * 8];
#pragma unroll
      for (int j = 0; j < BNF; ++j)
        bfr[j] = *(const bf16x8*)&L[((NA + ks * NTB + nw + j) * 64 + lane) * 8];
      __builtin_amdgcn_s_setprio(1);
#pragma unroll
      for (int i = 0; i < AM; ++i)
#pragma unroll
        for (int j = 0; j < BNF; ++j)
          acc[i][j] = __builtin_amdgcn_mfma_f32_16x16x32_bf16(af[i], bfr[j], acc[i][j], 0, 0, 0);
      __builtin_amdgcn_s_setprio(0);
    }
  };

  const int nt = K >> 6;
  if constexpr (BUFS == 2) {
    stage(0, 0);
    int cur = 0;
    for (int t = 0; t < nt; ++t) {
      __syncthreads();
      if (t + 1 < nt) stage((t + 1) << 6, cur ^ 1);
      mfma_step(lds[cur]);
      cur ^= 1;
    }
  } else {
    stage(0, 0);
    stage(64, 1);
    int cur = 0;
    for (int t = 0; t < nt; ++t) {
      if (t + 1 < nt) {
        if (LPTR != 0 && wave < LPTR) asm volatile("s_waitcnt vmcnt(%0)" :: "i"(LPTH) : "memory");
        else                          asm volatile("s_waitcnt vmcnt(%0)" :: "i"(LLO) : "memory");
      } else {
        asm volatile("s_waitcnt vmcnt(0)" ::: "memory");
      }
      __builtin_amdgcn_sched_barrier(0);
      __builtin_amdgcn_s_barrier();
      __builtin_amdgcn_sched_barrier(0);
      int nxt = cur + 2; if (nxt >= 3) nxt -= 3;
      if (t + 2 < nt) stage((t + 2) << 6, nxt);
      mfma_step(lds[cur]);
      if (++cur == 3) cur = 0;
    }
  }

#pragma unroll
  for (int i = 0; i < AM; ++i) {
#pragma unroll
    for (int j = 0; j < BNF; ++j) {
      int c = nBase + (nw + j) * 16 + r16;
      float bb = bias[c];
#pragma unroll
      for (int e = 0; e < 4; ++e) {
        int r = mBase + (mw + i) * 16 + g * 4 + e;
        float val = acc[i][j][e] + bb;
        if (EPI == 0) {
          int which = c / 768;             // 0:q 1:k 2:v
          int cc = c - which * 768;
          int hh = cc >> 6, dd = cc & 63;
          int bI = r >> 11, tt = r & 2047;
          if (which == 0) {
            // fold 1/sqrt(64) * log2(e) into q (softmax runs in exp2 space)
            qo[(((size_t)(bI * 12 + hh)) * 2048 + tt) * 64 + dd] = (__bf16)(val * 0.180336880f);
          } else if (which == 1) {
            ko[(((size_t)(bI * 12 + hh)) * 2048 + tt) * 64 + dd] = (__bf16)val;
          } else {
            vo[(((size_t)(bI * 12 + hh)) * 64 + dd) * 2048 + tt] = (__bf16)val;  // V^T [B,H,64,T]
          }
        } else {
          outF[(size_t)r * N + c] = val;
        }
      }
    }
  }
}

// Flash attention, causal, swapped-QK^T, O^T accumulation, causal-paired tiles,
// strip-split 4-wave blocks. R12-EXACT (best measured attn variant):
// 768 uniform blocks (3/CU), wave w owns ONE 16-row q-strip (waves 0,1 = tile p
// [Kt=Kp], waves 2,3 = tile a [Kt=Ka<Kp]); untracked softmax in exp2 space.
__global__ __launch_bounds__(256, 2)
void attn_kernel(const __bf16* __restrict__ qg, const __bf16* __restrict__ kg,
                 const __bf16* __restrict__ vtg, __bf16* __restrict__ yatt) {
  const int id = blockIdx.x;
  const int chunk = id & 7, within = id >> 3;   // XCD chunk = 3 heads (L2-resident K/V)
  const int bh = chunk * 3 + (within >> 5);
  const int a = within & 31, p = 63 - a;        // paired 32-row q-tiles
  const int Ka = (a >> 1) + 1, Kp = (p >> 1) + 1;   // Kp > Ka always
  const int lane = threadIdx.x & 63, wave = threadIdx.x >> 6;  // wave 0..3
  const int r16 = lane & 15, g = lane >> 4;
  const int bI = bh / 12, h = bh - bI * 12;
  const size_t headoff = (size_t)bh * 2048 * 64;
  const __bf16* Q = qg + headoff;
  const __bf16* Kh = kg + headoff;
  const __bf16* VT = vtg + headoff;             // [64][2048]

  __shared__ __align__(16) __bf16 Kbuf[2][4096];   // [64 k-rows][8 chunks] swizzled
  __shared__ __align__(16) __bf16 Vbuf[2][4096];   // [64 d-rows][8 chunks] swizzled
  __shared__ __align__(16) __bf16 Plds[4][16][72]; // per-wave strip

  const int myTile = (wave < 2) ? p : a;
  const int myKt   = (wave < 2) ? Kp : Ka;
  const int rowQ   = myTile * 32 + (wave & 1) * 16 + r16;

  bf16x8 qf[2];
#pragma unroll
  for (int ks = 0; ks < 2; ++ks)
    qf[ks] = *(const bf16x8*)&Q[(size_t)rowQ * 64 + ks * 32 + g * 8];

  int srow[2], scl[2];
#pragma unroll
  for (int i = 0; i < 2; ++i) {
    int c = (i * 4 + wave) * 64 + lane;
    srow[i] = c >> 3;
    scl[i] = (c & 7) ^ (srow[i] & 7);
  }
  auto stage = [&](int kt, int b) {
#pragma unroll
    for (int i = 0; i < 2; ++i) {
      GLOAD_LDS16(&Kh[(size_t)(kt * 64 + srow[i]) * 64 + scl[i] * 8], &Kbuf[b][(i * 4 + wave) * 512]);
      GLOAD_LDS16(&VT[(size_t)srow[i] * 2048 + kt * 64 + scl[i] * 8], &Vbuf[b][(i * 4 + wave) * 512]);
    }
  };

  f32x4 o[4];
#pragma unroll
  for (int j = 0; j < 4; ++j) o[j] = (f32x4){0.f, 0.f, 0.f, 0.f};
  float l = 0.f;

  stage(0, 0);
  for (int kt = 0; kt < Kp; ++kt) {
    const int cur = kt & 1;
    __syncthreads();
    if (kt + 1 < Kp) stage(kt + 1, cur ^ 1);
    if (kt < myKt) {
      f32x4 st[4];
#pragma unroll
      for (int j = 0; j < 4; ++j) st[j] = (f32x4){0.f, 0.f, 0.f, 0.f};
      __builtin_amdgcn_s_setprio(1);
#pragma unroll
      for (int ks = 0; ks < 2; ++ks)
#pragma unroll
        for (int j = 0; j < 4; ++j) {
          int row = j * 16 + r16;
          int cp = (ks * 4 + g) ^ (row & 7);
          bf16x8 kf = *(const bf16x8*)&Kbuf[cur][(row * 8 + cp) * 8];
          st[j] = __builtin_amdgcn_mfma_f32_16x16x32_bf16(kf, qf[ks], st[j], 0, 0, 0);
        }
      __builtin_amdgcn_s_setprio(0);
      bf16x8 vf[2][4];
#pragma unroll
      for (int ks = 0; ks < 2; ++ks)
#pragma unroll
        for (int dj = 0; dj < 4; ++dj) {
          int row = dj * 16 + r16;
          int cp = (ks * 4 + g) ^ (row & 7);
          vf[ks][dj] = *(const bf16x8*)&Vbuf[cur][(row * 8 + cp) * 8];
        }
      if (kt == myKt - 1) {
#pragma unroll
        for (int j = 0; j < 4; ++j)
#pragma unroll
          for (int e = 0; e < 4; ++e)
            if (kt * 64 + j * 16 + 4 * g + e > rowQ) st[j][e] = -INFINITY;
      }
      float ls = 0.f;
#pragma unroll
      for (int j = 0; j < 4; ++j)
#pragma unroll
        for (int e = 0; e < 4; ++e) {
          float pv = fexp2(st[j][e]);
          st[j][e] = pv;
          ls += pv;
        }
      ls += __shfl_xor(ls, 16, 64);
      ls += __shfl_xor(ls, 32, 64);
      l += ls;
#pragma unroll
      for (int j = 0; j < 4; ++j) {
        bf16x4 pk;
#pragma unroll
        for (int e = 0; e < 4; ++e) pk[e] = (__bf16)st[j][e];
        *(bf16x4*)&Plds[wave][r16][j * 16 + 4 * g] = pk;
      }
      __builtin_amdgcn_s_setprio(1);
#pragma unroll
      for (int ks = 0; ks < 2; ++ks) {
        bf16x8 pf = *(const bf16x8*)&Plds[wave][r16][ks * 32 + g * 8];
#pragma unroll
        for (int dj = 0; dj < 4; ++dj)
          o[dj] = __builtin_amdgcn_mfma_f32_16x16x32_bf16(vf[ks][dj], pf, o[dj], 0, 0, 0);
      }
      __builtin_amdgcn_s_setprio(0);
    }
  }

  float inv = 1.0f / l;
#pragma unroll
  for (int dj = 0; dj < 4; ++dj) {
    bf16x4 ov;
#pragma unroll
    for (int e = 0; e < 4; ++e) ov[e] = (__bf16)(o[dj][e] * inv);
    *(bf16x4*)&yatt[((size_t)(bI * 2048 + rowQ)) * 768 + h * 64 + dj * 16 + 4 * g] = ov;
  }
}

extern "C" void kernel_launch(void* const* d_in, const int* in_sizes, int n_in,
                              void* d_out, int out_size, void* d_ws, size_t ws_size,
                              hipStream_t stream) {
  (void)in_sizes; (void)n_in; (void)out_size; (void)ws_size;
  const float* x     = (const float*)d_in[0];
  const float* w_qkv = (const float*)d_in[1];
  const float* b_qkv = (const float*)d_in[2];
  const float* w_out = (const float*)d_in[3];
  const float* b_out = (const float*)d_in[4];
  float* out = (float*)d_out;

  char* ws = (char*)d_ws;
  __bf16* xb    = (__bf16*)(ws);              // [4096][768]
  __bf16* wqkvT = (__bf16*)(ws + 6291456);    // [2304][768]
  __bf16* woT   = (__bf16*)(ws + 9830400);    // [768][768]
  __bf16* qb    = (__bf16*)(ws + 11010048);   // [B,H,T,64]  (pre-scaled by 0.125*log2e)
  __bf16* kb    = (__bf16*)(ws + 17301504);   // [B,H,T,64]
  __bf16* vtb   = (__bf16*)(ws + 23592960);   // [B,H,64,T]  (V transposed)
  __bf16* yatt  = (__bf16*)(ws + 29884416);   // [4096][768]

  // one fused conversion launch (x -> bf16; w_qkv^T; w_out^T)
  cvt_fused_kernel<<<5376, 256, 0, stream>>>(x, xb, w_qkv, wqkvT, w_out, woT);
  // QKV: R14 config (best measured 41.9us): 128x288, 12 waves, 3-buf counted,
  // 256 blocks = exactly 1/CU; each XCD owns one 288-col B-slice (L2-resident).
  gemm_tn_kernel<0, 128, 288, 12, 2, 6, 3><<<256, 768, 0, stream>>>(
      xb, wqkvT, b_qkv, nullptr, qb, kb, vtb, 4096, 2304, 768, 8, 1, 32);
  // attn: R12-exact strip-split, 768 uniform blocks (3/CU)
  attn_kernel<<<768, 256, 0, stream>>>(qb, kb, vtb, yatt);
  // out-proj: 64x96 tiles, 512 blocks (2/CU), 3-buf counted; XCD rect 16x4
  gemm_tn_kernel<1, 64, 96, 4, 2, 2, 3><<<512, 256, 0, stream>>>(
      yatt, woT, b_out, out, nullptr, nullptr, nullptr, 4096, 768, 768, 8, 4, 16);
}